// Round 7
// baseline (46.320 us; speedup 1.0000x reference)
//
#include <hip/hip_runtime.h>

#define HH 56
#define WW 56
#define HWSZ 3136
#define KS 7
#define KK 49

typedef __attribute__((ext_vector_type(8))) short short8;
typedef __attribute__((ext_vector_type(4))) float f32x4;

__device__ inline unsigned short f2bf(float f) {
    unsigned u = __builtin_bit_cast(unsigned, f);
    u += 0x7FFF + ((u >> 16) & 1);          // RNE
    return (unsigned short)(u >> 16);
}
__device__ inline float bflo(unsigned u) { return __builtin_bit_cast(float, u << 16); }
__device__ inline float bfhi(unsigned u) { return __builtin_bit_cast(float, u & 0xFFFF0000u); }

// --------- Kernel A (MFMA, no LDS): t[p][64] = relu(BN(x @ w1^T)) in bf16 ---------
// grid 800: blocks 0..15 = w2->bf16 prep (1 group each); blocks 16..799 = 16-px tiles.
// Wave wv owns o-tile [wv*16,wv*16+16); A (w1) and B (x) fragments loaded straight
// from global into registers — zero LDS, zero syncthreads.
__global__ __launch_bounds__(256) void ka_mfma(
    const float* __restrict__ x, const float* __restrict__ w1,
    const float* __restrict__ gamma, const float* __restrict__ beta,
    const float* __restrict__ mean, const float* __restrict__ var,
    const float* __restrict__ w2,
    unsigned short* __restrict__ t_bf, unsigned short* __restrict__ w2p)
{
    const int tid = threadIdx.x;
    if (blockIdx.x < 16) {
        const int g = blockIdx.x;
        #pragma unroll
        for (int it = 0; it < 16; ++it) {
            const int i = it * 256 + tid;
            const int r = i >> 6, k = i & 63;
            float v = (r < KK) ? w2[(g * KK + r) * 64 + k] : 0.f;
            w2p[(size_t)(g * 64 + r) * 64 + k] = f2bf(v);
        }
        return;
    }

    const int tile = blockIdx.x - 16;
    const int p0 = tile * 16;                      // 16-px tile; 196 tiles per image
    const int b = p0 / HWSZ, hw0 = p0 - b * HWSZ;

    const int lane = tid & 63, wv = tid >> 6;
    const int m = lane & 15, q = lane >> 4;

    const float* xb   = x + (size_t)b * 256 * HWSZ + hw0 + m;   // B: px = p0+m
    const float* wrow = w1 + (wv * 16 + m) * 256 + q * 8;       // A: o = wv*16+m

    f32x4 acc = {0.f, 0.f, 0.f, 0.f};
    #pragma unroll
    for (int ks = 0; ks < 8; ++ks) {
        const int c0 = ks * 32 + q * 8;
        // B octet: x[c0+j][p0+m], 16-lane coalesced per q-group
        float xv[8];
        #pragma unroll
        for (int j = 0; j < 8; ++j)
            xv[j] = xb[(size_t)(c0 + j) * HWSZ];
        short8 bfr;
        #pragma unroll
        for (int j = 0; j < 8; ++j)
            bfr[j] = (short)f2bf(xv[j]);
        // A octet: w1[o][c0+j] (L2/L1-hot across blocks)
        float4 f0 = *(const float4*)(wrow + ks * 32);
        float4 f1 = *(const float4*)(wrow + ks * 32 + 4);
        short8 afr;
        afr[0] = (short)f2bf(f0.x); afr[1] = (short)f2bf(f0.y);
        afr[2] = (short)f2bf(f0.z); afr[3] = (short)f2bf(f0.w);
        afr[4] = (short)f2bf(f1.x); afr[5] = (short)f2bf(f1.y);
        afr[6] = (short)f2bf(f1.z); afr[7] = (short)f2bf(f1.w);
        acc = __builtin_amdgcn_mfma_f32_16x16x32_bf16(afr, bfr, acc, 0, 0, 0);
    }

    // D: col(lane&15)=px, row((lane>>4)*4+j)=o  — verified layout
    const int ob = wv * 16 + q * 4;
    float4 g4 = *(const float4*)&gamma[ob];
    float4 v4 = *(const float4*)&var[ob];
    float4 m4 = *(const float4*)&mean[ob];
    float4 b4 = *(const float4*)&beta[ob];
    float gg[4] = {g4.x, g4.y, g4.z, g4.w};
    float vv[4] = {v4.x, v4.y, v4.z, v4.w};
    float mm[4] = {m4.x, m4.y, m4.z, m4.w};
    float bb[4] = {b4.x, b4.y, b4.z, b4.w};
    unsigned r0 = 0, r1 = 0;
    #pragma unroll
    for (int j = 0; j < 4; ++j) {
        float sc = gg[j] * rsqrtf(vv[j] + 1e-5f);
        float sh = bb[j] - mm[j] * sc;
        float val = acc[j] * sc + sh;
        val = val > 0.f ? val : 0.f;
        unsigned hb = f2bf(val);
        if (j < 2) r0 |= hb << (16 * j);
        else       r1 |= hb << (16 * (j - 2));
    }
    const int p = p0 + m;
    *(uint2*)&t_bf[(size_t)p * 64 + ob] = make_uint2(r0, r1);
}

// --------- Kernel B: MFMA weight-GEMM (1 group) + pipelined dynamic conv ---------
// grid 3584 = 16 groups x 224 (b,h); block 256 (4 waves). blockIdx%8 == g%8 -> each
// XCD's L2 holds y for exactly 2 groups (3.2 MB) across all (b,h).
__global__ __launch_bounds__(256) void kb_fused(
    const float* __restrict__ y, const float* __restrict__ b2,
    const unsigned short* __restrict__ t_bf, const unsigned short* __restrict__ w2p,
    float* __restrict__ out)
{
    __shared__ __align__(16) unsigned short wgt[52 * 68];   // 7 KB

    const int tid = threadIdx.x;
    const int g = blockIdx.x & 15;
    const int bh = blockIdx.x >> 4;            // 0..223
    const int b = bh / HH, h = bh - b * HH;

    // ---- phase 1: MFMA  wgt[kk][px] = sum_k t[px][k] * w2p[g][kk][k] + b2 ----
    {
        const int lane = tid & 63, wv = tid >> 6;
        const int m = lane & 15, q = lane >> 4;
        const int pt = wv;                     // 4 waves = 4 pixel-tiles
        const int prow = b * HWSZ + h * WW + pt * 16 + m;
        const short8* ta = (const short8*)(t_bf + (size_t)prow * 64 + q * 8);
        short8 a0 = ta[0];                     // k = q*8 + 0..7
        short8 a1 = ta[4];                     // k = 32 + q*8 + 0..7
        f32x4 acc[4];
        #pragma unroll
        for (int mt = 0; mt < 4; ++mt) { acc[mt][0]=0.f; acc[mt][1]=0.f; acc[mt][2]=0.f; acc[mt][3]=0.f; }
        #pragma unroll
        for (int mt = 0; mt < 4; ++mt) {
            const short8* tb = (const short8*)(w2p +
                (size_t)(g * 64 + mt * 16 + m) * 64 + q * 8);
            short8 b0 = tb[0], b1 = tb[4];
            acc[mt] = __builtin_amdgcn_mfma_f32_16x16x32_bf16(a0, b0, acc[mt], 0, 0, 0);
            acc[mt] = __builtin_amdgcn_mfma_f32_16x16x32_bf16(a1, b1, acc[mt], 0, 0, 0);
        }
        // D: col(kk)=lane&15, row(px)=(lane>>4)*4+j
        #pragma unroll
        for (int mt = 0; mt < 4; ++mt) {
            const int kk = mt * 16 + m;
            if (kk < 52) {
                float bv = (kk < KK) ? b2[g * KK + kk] : 0.f;
                f32x4 v = acc[mt];
                unsigned r0 = (unsigned)f2bf(v[0] + bv) | ((unsigned)f2bf(v[1] + bv) << 16);
                unsigned r1 = (unsigned)f2bf(v[2] + bv) | ((unsigned)f2bf(v[3] + bv) << 16);
                const int pxb = pt * 16 + q * 4;
                *(uint2*)&wgt[kk * 68 + pxb] = make_uint2(r0, r1);
            }
        }
    }
    __syncthreads();

    // ---- phase 2: conv, 1 cc x 4 px per thread, 1-row-deep pipelined loads ----
    if (tid < 224) {
        const int cc = tid / 14, pq = tid - cc * 14;
        const unsigned short* wg = &wgt[pq * 4];
        const bool eL = (pq > 0), eR = (pq < 13);
        const int offL = eL ? 0 : 4;           // clamped, always in-bounds
        const int offR = eR ? 8 : 4;
        const float* yb0 = y + (size_t)(b * 256 + g * 16 + cc) * HWSZ + pq * 4 - 4;

        float4 cA0, cA1, cA2, nA0, nA1, nA2;
        {
            const int hs = h - 3;
            const int hsc = hs < 0 ? 0 : hs;
            const float* r0 = yb0 + hsc * WW;
            cA0 = *(const float4*)(r0 + offL);
            cA1 = *(const float4*)(r0 + 4);
            cA2 = *(const float4*)(r0 + offR);
        }
        float a00 = 0.f, a01 = 0.f, a02 = 0.f, a03 = 0.f;

        #pragma unroll
        for (int di = 0; di < KS; ++di) {
            if (di < 6) {                      // issue next row's loads first
                const int hs = h - 2 + di;
                const int hsc = hs < 0 ? 0 : (hs > HH - 1 ? HH - 1 : hs);
                const float* r0 = yb0 + hsc * WW;
                nA0 = *(const float4*)(r0 + offL);
                nA1 = *(const float4*)(r0 + 4);
                nA2 = *(const float4*)(r0 + offR);
            }
            const int hs = h - 3 + di;
            if ((unsigned)hs < HH) {           // block-uniform branch
                float w0[11];
                w0[1] = eL ? cA0.y : 0.f;  w0[2] = eL ? cA0.z : 0.f;  w0[3] = eL ? cA0.w : 0.f;
                w0[4] = cA1.x; w0[5] = cA1.y; w0[6] = cA1.z; w0[7] = cA1.w;
                w0[8] = eR ? cA2.x : 0.f;  w0[9] = eR ? cA2.y : 0.f;  w0[10] = eR ? cA2.z : 0.f;
                #pragma unroll
                for (int dj = 0; dj < KS; ++dj) {
                    uint2 wr = *(const uint2*)&wg[(di * KS + dj) * 68];
                    a00 += bflo(wr.x) * w0[dj + 1];
                    a01 += bfhi(wr.x) * w0[dj + 2];
                    a02 += bflo(wr.y) * w0[dj + 3];
                    a03 += bfhi(wr.y) * w0[dj + 4];
                }
            }
            if (di < 6) { cA0 = nA0; cA1 = nA1; cA2 = nA2; }
        }
        float* o0 = out + (size_t)(b * 256 + g * 16 + cc) * HWSZ + h * WW + pq * 4;
        *(float4*)o0 = make_float4(a00, a01, a02, a03);
    }
}

extern "C" void kernel_launch(void* const* d_in, const int* in_sizes, int n_in,
                              void* d_out, int out_size, void* d_ws, size_t ws_size,
                              hipStream_t stream) {
    const float* x     = (const float*)d_in[0];
    const float* y     = (const float*)d_in[1];
    const float* w1    = (const float*)d_in[2];
    const float* gamma = (const float*)d_in[3];
    const float* beta  = (const float*)d_in[4];
    const float* mean  = (const float*)d_in[5];
    const float* var   = (const float*)d_in[6];
    const float* w2    = (const float*)d_in[7];
    const float* b2    = (const float*)d_in[8];
    float* out = (float*)d_out;

    unsigned short* t_bf = (unsigned short*)d_ws;          // [12608][64] bf16 (pad rows)
    unsigned short* w2p  = t_bf + (size_t)12608 * 64;      // [16*64][64] bf16

    ka_mfma<<<800, 256, 0, stream>>>(x, w1, gamma, beta, mean, var, w2, t_bf, w2p);
    kb_fused<<<3584, 256, 0, stream>>>(y, b2, t_bf, w2p, out);
}